// Round 1
// baseline (642.826 us; speedup 1.0000x reference)
//
#include <hip/hip_runtime.h>

#define PATCH 4
#define EMBED 96
#define HIN 512
#define WIN 512
#define HP 128
#define WP 128
#define BATCH 8
#define CHAN 8   // 3 rgb + 4 hs + 1 dem

// v2: write-locality restructure.
// Grid: 1024 blocks = 64 planes (b,c) x 16 hp-groups (8 hp rows each).
// Block: 256 threads; thread = (hp_local = tid>>5, wp4 = (tid&31)*4).
// Each thread owns 4 adjacent wp patches for all 96 e:
//   - loads its 4 rows x 16 floats once (16x global_load_dwordx4, coalesced:
//     lanes 0..31 cover 2048B contiguous per image row)
//   - per e: 64 FMA from registers + uniform (scalar-cached) W loads,
//     one float4 store -> 1KB contiguous per wave-instruction,
//     4KB contiguous per block per e-slice (was 256B chunks).
// XCD swizzle: the 16 blocks of one plane share an XCD (blockIdx%8 round-robin),
// so each L2's write stream stays inside one 6MB plane region.
__global__ __launch_bounds__(256, 4)
void patch_embed_kernel(const float* __restrict__ rgb,
                        const float* __restrict__ hs,
                        const float* __restrict__ dem,
                        const float* __restrict__ W,
                        const float* __restrict__ bias,
                        float* __restrict__ out) {
    const int d     = blockIdx.x;            // 0..1023
    const int xcd   = d & 7;
    const int j     = d >> 3;                // 0..127
    const int plane = (j >> 4) * 8 + xcd;    // 0..63 == b*8 + c (bijective)
    const int hp8   = j & 15;                // hp group of 8 rows
    const int b = plane >> 3;
    const int c = plane & 7;

    const int tid = threadIdx.x;
    const int hp  = hp8 * 8 + (tid >> 5);    // 0..127
    const int wp4 = (tid & 31) * 4;          // first of 4 wp patches (0,4,..,124)

    // channel -> source plane (concat order: rgb[0..2], hs[3..6], dem[7])
    const float* src;
    if (c < 3)      src = rgb + (size_t)(b * 3 + c)       * (HIN * WIN);
    else if (c < 7) src = hs  + (size_t)(b * 4 + (c - 3)) * (HIN * WIN);
    else            src = dem + (size_t)b                 * (HIN * WIN);

    const float* base = src + (size_t)(hp * PATCH) * WIN + wp4 * PATCH;

    // q[r][k] = row r (of 4) of patch k (of 4): 64 floats in registers.
    float4 q[4][4];
    #pragma unroll
    for (int r = 0; r < 4; ++r) {
        #pragma unroll
        for (int k = 0; k < 4; ++k) {
            q[r][k] = *(const float4*)(base + (size_t)r * WIN + k * PATCH);
        }
    }

    // out[b, c*96+e, hp, wp4..wp4+3]; e-slice stride = HP*WP floats (64 KB)
    float* outp = out + (((size_t)plane * EMBED * HP + hp) * WP + wp4);

    #pragma unroll 2
    for (int e = 0; e < EMBED; ++e) {
        float4 w[4];
        #pragma unroll
        for (int r = 0; r < 4; ++r) {
            w[r] = *(const float4*)(W + e * 16 + r * 4);  // uniform -> s_load
        }
        const float bb = bias[e];
        float acc[4];
        #pragma unroll
        for (int k = 0; k < 4; ++k) acc[k] = bb;

        #pragma unroll
        for (int r = 0; r < 4; ++r) {
            #pragma unroll
            for (int k = 0; k < 4; ++k) {
                acc[k] = fmaf(q[r][k].x, w[r].x, acc[k]);
                acc[k] = fmaf(q[r][k].y, w[r].y, acc[k]);
                acc[k] = fmaf(q[r][k].z, w[r].z, acc[k]);
                acc[k] = fmaf(q[r][k].w, w[r].w, acc[k]);
            }
        }

        *(float4*)(outp + (size_t)e * (HP * WP)) =
            make_float4(acc[0], acc[1], acc[2], acc[3]);
    }
}

extern "C" void kernel_launch(void* const* d_in, const int* in_sizes, int n_in,
                              void* d_out, int out_size, void* d_ws, size_t ws_size,
                              hipStream_t stream) {
    const float* rgb  = (const float*)d_in[0];
    const float* hs   = (const float*)d_in[1];
    const float* dem  = (const float*)d_in[2];
    const float* W    = (const float*)d_in[3];
    const float* bias = (const float*)d_in[4];
    float* out = (float*)d_out;

    const int grid = BATCH * CHAN * (HP / 8);   // 8*8*16 = 1024 blocks
    patch_embed_kernel<<<grid, 256, 0, stream>>>(rgb, hs, dem, W, bias, out);
}